// Round 17
// baseline (321.776 us; speedup 1.0000x reference)
//
#include <hip/hip_runtime.h>
#include <stdint.h>

// Pipeline (r16-validated structure; dense1 de-LDS'd via 4x partial buffer):
// img (8,160,240,3) -> conv1 6x6 (+fused 2x2 pool) -> (8,77,117,32)
// -> conv2 3x3 (+fused 2x2 pool) -> (8,37,57,64)
// -> conv3 3x3 -> (8,35,55,128) -> flatten 246400 -> dense 256 -> dense 38400
// (dense2 fused with reduce1b + predict_transform) -> pred + boxes
// NMS: sort -> grid-parallel IoU bit-matrix -> register-chain linear scan.

static __device__ __forceinline__ float sigmoidf_(float x) {
  return 1.0f / (1.0f + expf(-x));
}

// ---------------- conv1 6x6x3->32 + fused 2x2 maxpool ----------------
__global__ __launch_bounds__(256) void k_conv1p(const float* __restrict__ in,
    const float* __restrict__ w, const float* __restrict__ bias, float* __restrict__ out) {
  __shared__ float s_in[3 * 21 * 40];    // [c][y][x] padded rows
  __shared__ float s_w[6 * 6 * 3 * 32];  // [ky][kx][c][o]
  int tx = blockIdx.x, ty = blockIdx.y, n = blockIdx.z;
  int tid = threadIdx.x;
  int iy0 = ty * 16, ix0 = tx * 32;
  for (int idx = tid; idx < 3456; idx += 256) s_w[idx] = w[idx];
  for (int idx = tid; idx < 21 * 37 * 3; idx += 256) {
    int c = idx % 3;
    int rem = idx / 3;
    int x = rem % 37, y = rem / 37;
    int gy = iy0 + y, gx = ix0 + x;
    float v = 0.f;
    if (gy < 160 && gx < 240) v = in[((size_t)(n * 160 + gy) * 240 + gx) * 3 + c];
    s_in[c * 840 + y * 40 + x] = v;
  }
  __syncthreads();

  int cg = tid >> 6;
  int l = tid & 63;
  int py = l >> 2;
  int px0 = (l & 3) * 8;

  float acc[8][8];
  float bj[8];
#pragma unroll
  for (int j = 0; j < 8; j++) bj[j] = bias[cg * 8 + j];
#pragma unroll
  for (int k = 0; k < 8; k++)
#pragma unroll
    for (int j = 0; j < 8; j++) acc[k][j] = bj[j];

#pragma unroll 1
  for (int ky = 0; ky < 6; ky++) {
#pragma unroll 1
    for (int c = 0; c < 3; c++) {
      const float* ib = s_in + c * 840 + (py + ky) * 40 + px0;
      float4 q0 = ((const float4*)ib)[0];
      float4 q1 = ((const float4*)ib)[1];
      float4 q2 = ((const float4*)ib)[2];
      float4 q3 = ((const float4*)ib)[3];
      float iv16[16] = {q0.x, q0.y, q0.z, q0.w, q1.x, q1.y, q1.z, q1.w,
                        q2.x, q2.y, q2.z, q2.w, q3.x, q3.y, q3.z, q3.w};
#pragma unroll
      for (int kx = 0; kx < 6; kx++) {
        const float* wb = s_w + ((ky * 6 + kx) * 3 + c) * 32 + cg * 8;
        float4 wva = *(const float4*)wb;
        float4 wvb = *(const float4*)(wb + 4);
        float wv[8] = {wva.x, wva.y, wva.z, wva.w, wvb.x, wvb.y, wvb.z, wvb.w};
#pragma unroll
        for (int k = 0; k < 8; k++)
#pragma unroll
          for (int j = 0; j < 8; j++) acc[k][j] = fmaf(iv16[kx + k], wv[j], acc[k][j]);
      }
    }
  }
  float pm[4][8];
#pragma unroll
  for (int kk = 0; kk < 4; kk++)
#pragma unroll
    for (int j = 0; j < 8; j++) pm[kk][j] = fmaxf(acc[2 * kk][j], acc[2 * kk + 1][j]);
#pragma unroll
  for (int kk = 0; kk < 4; kk++)
#pragma unroll
    for (int j = 0; j < 8; j++) {
      float o = __shfl_down(pm[kk][j], 4);
      pm[kk][j] = fmaxf(pm[kk][j], o);
    }
  if (!(py & 1)) {
    int pyp = ty * 8 + (py >> 1);
    if (pyp < 77) {
#pragma unroll
      for (int kk = 0; kk < 4; kk++) {
        int pxp = tx * 16 + (l & 3) * 4 + kk;
        if (pxp < 117) {
          float* op = out + ((size_t)(n * 77 + pyp) * 117 + pxp) * 32 + cg * 8;
          float4 v0, v1;
          v0.x = fmaxf(pm[kk][0], 0.f); v0.y = fmaxf(pm[kk][1], 0.f);
          v0.z = fmaxf(pm[kk][2], 0.f); v0.w = fmaxf(pm[kk][3], 0.f);
          v1.x = fmaxf(pm[kk][4], 0.f); v1.y = fmaxf(pm[kk][5], 0.f);
          v1.z = fmaxf(pm[kk][6], 0.f); v1.w = fmaxf(pm[kk][7], 0.f);
          ((float4*)op)[0] = v0;
          ((float4*)op)[1] = v1;
        }
      }
    }
  }
}

// ---------------- conv2 3x3x32->64 + fused 2x2 maxpool (256 thr, 4ch/thread) ------
__global__ __launch_bounds__(256) void k_conv2p(const float* __restrict__ in,
    const float* __restrict__ w, const float* __restrict__ bias, float* __restrict__ out) {
  __shared__ float s_in[32 * 10 * 20];  // [c][y][x] padded rows
  int tx = blockIdx.x, ty = blockIdx.y, n = blockIdx.z;
  int tid = threadIdx.x;
  int iy0 = ty * 8, ix0 = tx * 16;
  for (int idx = tid; idx < 10 * 18 * 32; idx += 256) {
    int c = idx & 31;
    int rem = idx >> 5;
    int x = rem % 18, y = rem / 18;
    int gy = iy0 + y, gx = ix0 + x;
    float v = 0.f;
    if (gy < 77 && gx < 117) v = in[((size_t)(n * 77 + gy) * 117 + gx) * 32 + c];
    s_in[c * 200 + y * 20 + x] = v;
  }
  __syncthreads();

  int cg = tid >> 4;   // 16 groups x 4 out-ch
  int pg = tid & 15;
  int py = pg >> 1;
  int px0 = (pg & 1) * 8;

  float acc[8][4];
  float bj[4];
#pragma unroll
  for (int j = 0; j < 4; j++) bj[j] = bias[cg * 4 + j];
#pragma unroll
  for (int k = 0; k < 8; k++)
#pragma unroll
    for (int j = 0; j < 4; j++) acc[k][j] = bj[j];

#pragma unroll 1
  for (int ky = 0; ky < 3; ky++) {
#pragma unroll 2
    for (int c = 0; c < 32; c++) {
      const float* ib = s_in + c * 200 + (py + ky) * 20 + px0;
      float4 q0 = ((const float4*)ib)[0];
      float4 q1 = ((const float4*)ib)[1];
      float4 q2 = ((const float4*)ib)[2];
      float iv12[12] = {q0.x, q0.y, q0.z, q0.w, q1.x, q1.y, q1.z, q1.w,
                        q2.x, q2.y, q2.z, q2.w};
#pragma unroll
      for (int kx = 0; kx < 3; kx++) {
        float4 wa = *(const float4*)(w + (size_t)((ky * 3 + kx) * 32 + c) * 64 + cg * 4);
#pragma unroll
        for (int k = 0; k < 8; k++) {
          acc[k][0] = fmaf(iv12[kx + k], wa.x, acc[k][0]);
          acc[k][1] = fmaf(iv12[kx + k], wa.y, acc[k][1]);
          acc[k][2] = fmaf(iv12[kx + k], wa.z, acc[k][2]);
          acc[k][3] = fmaf(iv12[kx + k], wa.w, acc[k][3]);
        }
      }
    }
  }
  float pm[4][4];
#pragma unroll
  for (int kk = 0; kk < 4; kk++)
#pragma unroll
    for (int j = 0; j < 4; j++) pm[kk][j] = fmaxf(acc[2 * kk][j], acc[2 * kk + 1][j]);
#pragma unroll
  for (int kk = 0; kk < 4; kk++)
#pragma unroll
    for (int j = 0; j < 4; j++) {
      float o = __shfl_down(pm[kk][j], 2);
      pm[kk][j] = fmaxf(pm[kk][j], o);
    }
  if (!(pg & 2)) {
    int pyp = ty * 4 + (py >> 1);
    if (pyp < 37) {
#pragma unroll
      for (int kk = 0; kk < 4; kk++) {
        int pxp = tx * 8 + (pg & 1) * 4 + kk;
        if (pxp < 57) {
          float* op = out + ((size_t)(n * 37 + pyp) * 57 + pxp) * 64 + cg * 4;
          float4 v0;
          v0.x = fmaxf(pm[kk][0], 0.f); v0.y = fmaxf(pm[kk][1], 0.f);
          v0.z = fmaxf(pm[kk][2], 0.f); v0.w = fmaxf(pm[kk][3], 0.f);
          ((float4*)op)[0] = v0;
        }
      }
    }
  }
}

// ---------------- conv3: 3x3x64 -> 128, 4-row tiles, channel-split x2 ----------------
__global__ __launch_bounds__(256) void k_conv3(const float* __restrict__ in,
    const float* __restrict__ w, const float* __restrict__ bias, float* __restrict__ out) {
  __shared__ float s_in[64 * 6 * 20];  // [c][y][x] padded rows
  int tx = blockIdx.x, ty = blockIdx.y, z = blockIdx.z;
  int n = z >> 1, h = z & 1;
  int tid = threadIdx.x;
  int iy0 = ty * 4, ix0 = tx * 16;
  for (int idx = tid; idx < 6 * 18 * 64; idx += 256) {
    int c = idx & 63;
    int rem = idx >> 6;
    int x = rem % 18, y = rem / 18;
    int gy = iy0 + y, gx = ix0 + x;
    float v = 0.f;
    if (gy < 37 && gx < 57) v = in[((size_t)(n * 37 + gy) * 57 + gx) * 64 + c];
    s_in[c * 120 + y * 20 + x] = v;
  }
  __syncthreads();

  int cg = tid >> 4;
  int pg = tid & 15;
  int py = pg >> 2;
  int px0 = (pg & 3) * 4;
  int ob = h * 64 + cg * 4;

  float acc[4][4];
  float bj[4];
#pragma unroll
  for (int j = 0; j < 4; j++) bj[j] = bias[ob + j];
#pragma unroll
  for (int k = 0; k < 4; k++)
#pragma unroll
    for (int j = 0; j < 4; j++) acc[k][j] = bj[j];

#pragma unroll 1
  for (int ky = 0; ky < 3; ky++) {
#pragma unroll 2
    for (int c = 0; c < 64; c++) {
      const float* ib = s_in + c * 120 + (py + ky) * 20 + px0;
      float4 q0 = ((const float4*)ib)[0];
      float4 q1 = ((const float4*)ib)[1];
      float iv8[8] = {q0.x, q0.y, q0.z, q0.w, q1.x, q1.y, q1.z, q1.w};
#pragma unroll
      for (int kx = 0; kx < 3; kx++) {
        float4 wa = *(const float4*)(w + (size_t)((ky * 3 + kx) * 64 + c) * 128 + ob);
#pragma unroll
        for (int k = 0; k < 4; k++) {
          acc[k][0] = fmaf(iv8[kx + k], wa.x, acc[k][0]);
          acc[k][1] = fmaf(iv8[kx + k], wa.y, acc[k][1]);
          acc[k][2] = fmaf(iv8[kx + k], wa.z, acc[k][2]);
          acc[k][3] = fmaf(iv8[kx + k], wa.w, acc[k][3]);
        }
      }
    }
  }
  int oy = iy0 + py;
  if (oy < 35) {
#pragma unroll
    for (int k = 0; k < 4; k++) {
      int ox = ix0 + px0 + k;
      if (ox < 55) {
        float* op = out + ((size_t)(n * 35 + oy) * 55 + ox) * 128 + ob;
        float4 v0;
        v0.x = fmaxf(acc[k][0], 0.f); v0.y = fmaxf(acc[k][1], 0.f);
        v0.z = fmaxf(acc[k][2], 0.f); v0.w = fmaxf(acc[k][3], 0.f);
        ((float4*)op)[0] = v0;
      }
    }
  }
}

// ---------------- dense1: per-wave partials straight to global (no red LDS) ----------
// 963 blocks; thread (c4, ks): 4 cols x 8 n over 64 rows; wave ks writes its own
// 2048-slot partial: part4[(c*4+ks)*2048 + n*256 + col].
__global__ __launch_bounds__(256) void k_dense1(const float* __restrict__ a3,
    const float* __restrict__ wd1, float* __restrict__ part4) {
  __shared__ float s_x[256][8];
  int c = blockIdx.x;
  int tid = threadIdx.x;
  int c4 = tid & 63;
  int ks = tid >> 6;
  int k0 = c * 256;
  int kn = 246400 - k0;
  if (kn > 256) kn = 256;
  for (int idx = tid; idx < 2048; idx += 256) {
    int nn = idx >> 8, r = idx & 255;
    int rr = k0 + r;
    if (rr > 246399) rr = 246399;
    s_x[r][nn] = a3[(size_t)nn * 246400 + rr];
  }
  __syncthreads();
  float acc[8][4];
#pragma unroll
  for (int n = 0; n < 8; n++)
#pragma unroll
    for (int j = 0; j < 4; j++) acc[n][j] = 0.f;
  int kbeg = ks * 64;
  int kend = kbeg + 64;
  if (kend > kn) kend = kn;
#pragma unroll 8
  for (int kk = kbeg; kk < kend; kk++) {
    float4 wv = *(const float4*)(wd1 + (size_t)(k0 + kk) * 256 + c4 * 4);
    float4 xa = *(const float4*)&s_x[kk][0];
    float4 xb = *(const float4*)&s_x[kk][4];
    float xs[8] = {xa.x, xa.y, xa.z, xa.w, xb.x, xb.y, xb.z, xb.w};
#pragma unroll
    for (int n = 0; n < 8; n++) {
      acc[n][0] = fmaf(xs[n], wv.x, acc[n][0]);
      acc[n][1] = fmaf(xs[n], wv.y, acc[n][1]);
      acc[n][2] = fmaf(xs[n], wv.z, acc[n][2]);
      acc[n][3] = fmaf(xs[n], wv.w, acc[n][3]);
    }
  }
  float* pp = part4 + ((size_t)c * 4 + ks) * 2048 + c4 * 4;
#pragma unroll
  for (int n = 0; n < 8; n++)
    *(float4*)(pp + n * 256) = make_float4(acc[n][0], acc[n][1], acc[n][2], acc[n][3]);
}

// ---------------- reduce1 stage A: 16 chunks of 241 wave-partials x 2048 ----------------
__global__ __launch_bounds__(256) void k_reduce1a(const float* __restrict__ part4,
    float* __restrict__ partr) {
  int bx = blockIdx.x;
  int t = blockIdx.y * 256 + threadIdx.x;
  int qbeg = bx * 241;
  int qend = qbeg + 241;
  if (qend > 3852) qend = 3852;
  float s = 0.f;
#pragma unroll 8
  for (int q = qbeg; q < qend; q++) s += part4[(size_t)q * 2048 + t];
  partr[(size_t)bx * 2048 + t] = s;
}

// ---------------- dense2 + reduce1b + transform fused ----------------
__global__ __launch_bounds__(256) void k_dense2t(const float* __restrict__ partr,
    const float* __restrict__ bd1, const float* __restrict__ wd2,
    const float* __restrict__ bd2, float* __restrict__ pred,
    float4* __restrict__ boxd4, float* __restrict__ meta) {
  __shared__ float red[8][32][33];  // padded
  __shared__ float s_d1[256][8];
  int jb = blockIdx.x;  // 0..299
  int tid = threadIdx.x;
  for (int idx = tid; idx < 2048; idx += 256) {
    int n = idx >> 8, j = idx & 255;
    float s = 0.f;
#pragma unroll
    for (int b = 0; b < 16; b++) s += partr[b * 2048 + idx];
    s_d1[j][n] = fmaxf(s + bd1[j], 0.f);
  }
  __syncthreads();
  int c4 = tid & 31;
  int ks = tid >> 5;
  int j0 = jb * 128 + c4 * 4;
  float acc[8][4];
#pragma unroll
  for (int n = 0; n < 8; n++)
#pragma unroll
    for (int j = 0; j < 4; j++) acc[n][j] = 0.f;
#pragma unroll 8
  for (int kk = 0; kk < 32; kk++) {
    int row = ks * 32 + kk;
    float4 wv = *(const float4*)(wd2 + (size_t)row * 38400 + j0);
    float4 xa = *(const float4*)&s_d1[row][0];
    float4 xb = *(const float4*)&s_d1[row][4];
    float xs[8] = {xa.x, xa.y, xa.z, xa.w, xb.x, xb.y, xb.z, xb.w};
#pragma unroll
    for (int n = 0; n < 8; n++) {
      acc[n][0] = fmaf(xs[n], wv.x, acc[n][0]);
      acc[n][1] = fmaf(xs[n], wv.y, acc[n][1]);
      acc[n][2] = fmaf(xs[n], wv.z, acc[n][2]);
      acc[n][3] = fmaf(xs[n], wv.w, acc[n][3]);
    }
  }
#pragma unroll
  for (int n = 0; n < 8; n++)
#pragma unroll
    for (int j = 0; j < 4; j++) red[ks][c4][n * 4 + j] = acc[n][j];
  __syncthreads();
  if (tid >= 64) return;
  int n = tid >> 3, cc = tid & 7;
  int cell = jb * 8 + cc;  // 0..2399
  float v[16];
#pragma unroll
  for (int q = 0; q < 16; q++) {
    int lc = cc * 16 + q;
    int cq = lc >> 2, jq = lc & 3;
    float s = 0.f;
#pragma unroll
    for (int g = 0; g < 8; g++) s += red[g][cq][n * 4 + jq];
    v[q] = s + bd2[jb * 128 + lc];
  }
  float gx = (float)(cell % 60), gy = (float)(cell / 60);
  float o[16];
  o[0] = (sigmoidf_(v[0]) + gx) * 4.0f;
  o[1] = (sigmoidf_(v[1]) + gy) * 4.0f;
  o[2] = expf(v[2]) * 60.0f * 4.0f;
  o[3] = expf(v[3]) * 30.0f * 4.0f;
  o[4] = sigmoidf_(v[4]);
  o[5] = sigmoidf_(v[5]);
  o[6] = sigmoidf_(v[6]);
  o[7] = sigmoidf_(v[7]);
  o[8] = (v[8] + gx) * 4.0f;
  o[9] = (v[9] + gy) * 4.0f;
  o[10] = expf(v[10]) * 20.0f * 4.0f;
  o[11] = expf(v[11]) * 40.0f * 4.0f;
  o[12] = v[12];
  o[13] = sigmoidf_(v[13]);
  o[14] = sigmoidf_(v[14]);
  o[15] = sigmoidf_(v[15]);
  float* op = pred + ((size_t)n * 2400 + cell) * 16;
#pragma unroll
  for (int q4 = 0; q4 < 4; q4++) {
    float4 w4;
    w4.x = o[q4 * 4 + 0]; w4.y = o[q4 * 4 + 1];
    w4.z = o[q4 * 4 + 2]; w4.w = o[q4 * 4 + 3];
    ((float4*)op)[q4] = w4;
  }
#pragma unroll
  for (int h = 0; h < 2; h++) {
    int b = n * 4800 + h * 2400 + cell;
    float X = o[h * 8 + 0], Y = o[h * 8 + 1], W = o[h * 8 + 2], H = o[h * 8 + 3];
    float conf = o[h * 8 + 4];
    float c0 = o[h * 8 + 5], c1 = o[h * 8 + 6], c2 = o[h * 8 + 7];
    int cls = 0; float best = c0;
    if (c1 > best) { best = c1; cls = 1; }
    if (c2 > best) { best = c2; cls = 2; }
    float x1 = X - W / 2.0f, y1 = Y - H / 2.0f;
    float x2 = X + W / 2.0f, y2 = Y + H / 2.0f;
    boxd4[b] = make_float4(x1, y1, x2, y2);
    meta[2 * b] = conf;
    ((int*)meta)[2 * b + 1] = cls;
  }
}

// ---------------- NMS stage 1: zero keep + compact + sort (512 thr) ----------------
__global__ __launch_bounds__(512) void k_nms_sort(const float4* __restrict__ boxd4,
    const float* __restrict__ meta, int* __restrict__ cnt,
    float4* __restrict__ sbf, int* __restrict__ sidx, float* __restrict__ keep_out) {
  __shared__ unsigned long long key[8192];
  __shared__ int scnt;
  int bid = blockIdx.x;  // 0..23
  int n = bid / 3, c = bid - n * 3;
  int tid = threadIdx.x;
  float* ko = keep_out + (size_t)bid * 4800;
  for (int s = tid; s < 4800; s += 512) ko[s] = 0.f;
  if (tid == 0) scnt = 0;
  __syncthreads();

  const float* mt = meta + (size_t)n * 9600;
  for (int p = tid; p < 4800; p += 512) {
    float2 m = ((const float2*)mt)[p];
    float conf = m.x;
    int cls = __float_as_int(m.y);
    if (conf > 0.5f && cls == c) {
      int slot = atomicAdd(&scnt, 1);
      unsigned u = __float_as_uint(conf);
      unsigned asc = (u & 0x80000000u) ? ~u : (u | 0x80000000u);
      key[slot] = (((unsigned long long)(~asc)) << 32) | (unsigned)p;
    }
  }
  __syncthreads();
  int V = scnt;
  if (tid == 0) cnt[bid] = V;
  if (V == 0) return;
  int Vp2 = 1;
  while (Vp2 < V) Vp2 <<= 1;
  for (int s = V + tid; s < Vp2; s += 512) key[s] = ~0ull;

  // bitonic sort ascending -> score desc, idx asc (stable argsort(-score))
  for (int k = 2; k <= Vp2; k <<= 1) {
    for (int j = k >> 1; j > 0; j >>= 1) {
      __syncthreads();
      int jm = j - 1;
      for (int t2 = tid; t2 < (Vp2 >> 1); t2 += 512) {
        int i = ((t2 & ~jm) << 1) | (t2 & jm);
        int q = i | j;
        bool up = ((i & k) == 0);
        unsigned long long a = key[i], b2 = key[q];
        if ((a > b2) == up) { key[i] = b2; key[q] = a; }
      }
    }
  }
  __syncthreads();
  float4* sb = sbf + (size_t)bid * 4800;
  int* si = sidx + (size_t)bid * 4800;
  const float4* bsrc = boxd4 + (size_t)n * 4800;
  for (int s = tid; s < V; s += 512) {
    unsigned p = (unsigned)(key[s] & 0xFFFFFFFFull);
    sb[s] = bsrc[p];
    si[s] = (int)p;
  }
}

// ---------------- NMS stage 2: grid-parallel suppression bit-matrix ----------------
// grid (24, 16, 4): block = (nc, word-column w, row-quarter). Disjoint mat writes.
__global__ __launch_bounds__(256) void k_iou_mat(const int* __restrict__ cnt,
    const float4* __restrict__ sbf, unsigned long long* __restrict__ mat) {
  int nc = blockIdx.x;
  int w = blockIdx.y;
  int rz = blockIdx.z;
  int V = cnt[nc];
  if (V == 0 || V > 1024) return;
  int W = (V + 63) >> 6;
  if (w >= W) return;
  int chunk = (V + 3) >> 2;
  int rbeg = rz * chunk;
  int rend = rbeg + chunk;
  if (rend > V) rend = V;
  if (rbeg >= rend) return;
  int tid = threadIdx.x;
  int l = tid & 63, wv = tid >> 6;
  const float4* sb = sbf + (size_t)nc * 4800;
  int col = (w << 6) + l;
  float4 bj = sb[col < V ? col : (V - 1)];
  float aj = (bj.z - bj.x + 1.0f) * (bj.w - bj.y + 1.0f);
  unsigned long long* mrow = mat + (size_t)nc * 1024 * 16 + w;
  for (int i = rbeg + wv; i < rend; i += 4) {
    float4 bi = sb[i];  // wave-uniform, L2-hot
    float iw = fminf(bi.z, bj.z) - fmaxf(bi.x, bj.x) + 1.0f;
    float ih = fminf(bi.w, bj.w) - fmaxf(bi.y, bj.y) + 1.0f;
    iw = fmaxf(iw, 0.f);
    ih = fmaxf(ih, 0.f);
    float inter = iw * ih;
    float ai = (bi.z - bi.x + 1.0f) * (bi.w - bi.y + 1.0f);
    float iou = inter / (ai + aj - inter);
    bool pr = (col > i) && (col < V) && (iou >= 0.4f);
    unsigned long long word = __ballot(pr);
    if (l == 0) mrow[(size_t)i * 16] = word;
  }
}

// ---------------- NMS stage 3: linear greedy scan, VALU-only serial chain ----------------
__global__ __launch_bounds__(256) void k_nms_scan(const int* __restrict__ cnt,
    const unsigned long long* __restrict__ mat, const float4* __restrict__ sbf,
    const int* __restrict__ sidx, float* __restrict__ keep_out) {
  __shared__ float4 sbL[4800];            // slow-path staging
  __shared__ unsigned long long avail[75];
  int nc = blockIdx.x;
  int V = cnt[nc];
  if (V == 0) return;
  int tid = threadIdx.x;
  float* ko = keep_out + (size_t)nc * 4800;
  const int* si = sidx + (size_t)nc * 4800;

  if (V <= 1024) {
    if (tid >= 64) return;
    int l = tid;
    int W = (V + 63) >> 6;
    const unsigned long long* mbase = mat + (size_t)nc * 1024 * 16;
    bool act = (l < W);
    unsigned long long av = 0ull;  // lane l holds avail word l
    if (act) {
      int rem = V - (l << 6);
      av = (rem >= 64) ? ~0ull : ((1ull << rem) - 1ull);
    }
    unsigned long long mA[16], mB[16];
#pragma unroll
    for (int k = 0; k < 16; k++)
      mA[k] = (act && k < V) ? mbase[(size_t)k * 16 + l] : 0ull;
    for (int i0 = 0; i0 < V; i0 += 16) {
      int nx = i0 + 16;
#pragma unroll
      for (int k = 0; k < 16; k++)
        mB[k] = (act && (nx + k) < V) ? mbase[(size_t)(nx + k) * 16 + l] : 0ull;
      int wi = i0 >> 6;
      unsigned long long mloc[16];
#pragma unroll
      for (int k = 0; k < 16; k++) mloc[k] = __shfl(mA[k], wi, 64);
      unsigned long long cur = __shfl(av, wi, 64);
      unsigned alive = 0;
#pragma unroll
      for (int k = 0; k < 16; k++) {
        int i = i0 + k;
        if (i < V && ((cur >> (i & 63)) & 1ull)) {
          alive |= 1u << k;
          cur &= ~mloc[k];
        }
      }
#pragma unroll
      for (int k = 0; k < 16; k++)
        if ((alive >> k) & 1u) av &= ~mA[k];
      if (l < 16 && ((alive >> l) & 1u) && (i0 + l) < V) ko[si[i0 + l]] = 1.0f;
#pragma unroll
      for (int k = 0; k < 16; k++) mA[k] = mB[k];
    }
    return;
  }

  // slow path (V > 1024): r6-validated single-wave greedy
  {
    const float4* sb = sbf + (size_t)nc * 4800;
    for (int s = tid; s < V; s += 256) sbL[s] = sb[s];
    for (int w = tid; w < 75; w += 256) {
      int rem = V - (w << 6);
      avail[w] = (rem >= 64) ? ~0ull : (rem <= 0 ? 0ull : ((1ull << rem) - 1ull));
    }
    __syncthreads();
    if (tid >= 64) return;
    int l = tid;
    int wlast = (V - 1) >> 6;
    for (;;) {
      int cand = 0x7FFFFFFF;
      unsigned long long a0 = avail[l];
      if (a0) cand = (l << 6) + __ffsll((long long)a0) - 1;
      if (l < 11) {
        unsigned long long a1 = avail[64 + l];
        if (a1) {
          int c2 = ((64 + l) << 6) + __ffsll((long long)a1) - 1;
          if (c2 < cand) cand = c2;
        }
      }
#pragma unroll
      for (int off = 32; off > 0; off >>= 1) {
        int o = __shfl_xor(cand, off, 64);
        if (o < cand) cand = o;
      }
      if (cand == 0x7FFFFFFF) break;
      int i = cand;
      int tw = i >> 6;
      if (l == 0) {
        ko[si[i]] = 1.0f;
        avail[tw] &= ~(1ull << (i & 63));
      }
      float4 bi = sbL[i];
      float ai = (bi.z - bi.x + 1.0f) * (bi.w - bi.y + 1.0f);
      for (int w = tw; w <= wlast; w++) {
        unsigned long long aw = avail[w];
        if (!aw) continue;
        int col = (w << 6) + l;
        float4 bj = sbL[col];
        float iw = fminf(bi.z, bj.z) - fmaxf(bi.x, bj.x) + 1.0f;
        float ih = fminf(bi.w, bj.w) - fmaxf(bi.y, bj.y) + 1.0f;
        iw = fmaxf(iw, 0.f);
        ih = fmaxf(ih, 0.f);
        float inter = iw * ih;
        float aj = (bj.z - bj.x + 1.0f) * (bj.w - bj.y + 1.0f);
        float iou = inter / (ai + aj - inter);
        bool pr = (col > i) && (col < V) && (iou >= 0.4f);
        unsigned long long word = __ballot(pr);
        if (word && l == 0) avail[w] = aw & ~word;
      }
    }
  }
}

extern "C" void kernel_launch(void* const* d_in, const int* in_sizes, int n_in,
                              void* d_out, int out_size, void* d_ws, size_t ws_size,
                              hipStream_t stream) {
  const float* img = (const float*)d_in[0];
  const float* w1 = (const float*)d_in[1];
  const float* b1 = (const float*)d_in[2];
  const float* w2 = (const float*)d_in[3];
  const float* b2 = (const float*)d_in[4];
  const float* w3 = (const float*)d_in[5];
  const float* b3 = (const float*)d_in[6];
  const float* wd1 = (const float*)d_in[7];
  const float* bd1 = (const float*)d_in[8];
  const float* wd2 = (const float*)d_in[9];
  const float* bd2 = (const float*)d_in[10];

  float* ws = (float*)d_ws;
  // Liveness-checked layout (max 14,085,504 floats = 56.3 MB):
  float* a3 = ws + 0;                        // [0, 1,971,200)
  float* part4 = ws + 1971200;               // [1,971,200, 9,860,096) 3852*2048
  float* partr = ws + 9860096;               // 32,768
  float4* boxd4 = (float4*)(ws + 9892864);   // 153,600 floats
  float* meta = ws + 10046464;               // 76,800
  float4* sbf = (float4*)(ws + 10123264);    // 460,800
  int* sidx = (int*)(ws + 10584064);         // 115,200
  int* cnt = (int*)(ws + 10699264);          // 24
  float* p1 = ws + 10699392;                 // 2,306,304 pooled conv1 (dead after conv2p)
  float* p2 = ws + 13005696;                 // 1,079,808 pooled conv2 (dead after conv3)
  // mat overlays part4 (dead after reduce1a): 24*1024*16 u64 = 786,432 floats
  unsigned long long* mat = (unsigned long long*)(ws + 1971200);

  float* pred = (float*)d_out;
  float* keep = pred + 307200;

  k_conv1p<<<dim3(8, 10, 8), 256, 0, stream>>>(img, w1, b1, p1);
  k_conv2p<<<dim3(8, 10, 8), 256, 0, stream>>>(p1, w2, b2, p2);
  k_conv3<<<dim3(4, 9, 16), 256, 0, stream>>>(p2, w3, b3, a3);
  k_dense1<<<963, 256, 0, stream>>>(a3, wd1, part4);
  k_reduce1a<<<dim3(16, 8), 256, 0, stream>>>(part4, partr);
  k_dense2t<<<300, 256, 0, stream>>>(partr, bd1, wd2, bd2, pred, boxd4, meta);
  k_nms_sort<<<24, 512, 0, stream>>>(boxd4, meta, cnt, sbf, sidx, keep);
  k_iou_mat<<<dim3(24, 16, 4), 256, 0, stream>>>(cnt, sbf, mat);
  k_nms_scan<<<24, 256, 0, stream>>>(cnt, mat, sbf, sidx, keep);
}

// Round 18
// 307.419 us; speedup vs baseline: 1.0467x; 1.0467x over previous
//
#include <hip/hip_runtime.h>
#include <stdint.h>

// Pipeline (r16-validated config, exact revert):
// img (8,160,240,3) -> conv1 6x6 (+fused 2x2 pool) -> (8,77,117,32)
// -> conv2 3x3 (+fused 2x2 pool) -> (8,37,57,64)
// -> conv3 3x3 -> (8,35,55,128) -> flatten 246400 -> dense 256 -> dense 38400
// (dense2 fused with reduce1b + predict_transform) -> pred + boxes
// NMS: sort (512t) -> grid-parallel IoU bit-matrix (row-split) -> register scan.

static __device__ __forceinline__ float sigmoidf_(float x) {
  return 1.0f / (1.0f + expf(-x));
}

// ---------------- conv1 6x6x3->32 + fused 2x2 maxpool ----------------
__global__ __launch_bounds__(256) void k_conv1p(const float* __restrict__ in,
    const float* __restrict__ w, const float* __restrict__ bias, float* __restrict__ out) {
  __shared__ float s_in[3 * 21 * 40];    // [c][y][x] padded rows
  __shared__ float s_w[6 * 6 * 3 * 32];  // [ky][kx][c][o]
  int tx = blockIdx.x, ty = blockIdx.y, n = blockIdx.z;
  int tid = threadIdx.x;
  int iy0 = ty * 16, ix0 = tx * 32;
  for (int idx = tid; idx < 3456; idx += 256) s_w[idx] = w[idx];
  for (int idx = tid; idx < 21 * 37 * 3; idx += 256) {
    int c = idx % 3;
    int rem = idx / 3;
    int x = rem % 37, y = rem / 37;
    int gy = iy0 + y, gx = ix0 + x;
    float v = 0.f;
    if (gy < 160 && gx < 240) v = in[((size_t)(n * 160 + gy) * 240 + gx) * 3 + c];
    s_in[c * 840 + y * 40 + x] = v;
  }
  __syncthreads();

  int cg = tid >> 6;
  int l = tid & 63;
  int py = l >> 2;
  int px0 = (l & 3) * 8;

  float acc[8][8];
  float bj[8];
#pragma unroll
  for (int j = 0; j < 8; j++) bj[j] = bias[cg * 8 + j];
#pragma unroll
  for (int k = 0; k < 8; k++)
#pragma unroll
    for (int j = 0; j < 8; j++) acc[k][j] = bj[j];

#pragma unroll 1
  for (int ky = 0; ky < 6; ky++) {
#pragma unroll 1
    for (int c = 0; c < 3; c++) {
      const float* ib = s_in + c * 840 + (py + ky) * 40 + px0;
      float4 q0 = ((const float4*)ib)[0];
      float4 q1 = ((const float4*)ib)[1];
      float4 q2 = ((const float4*)ib)[2];
      float4 q3 = ((const float4*)ib)[3];
      float iv16[16] = {q0.x, q0.y, q0.z, q0.w, q1.x, q1.y, q1.z, q1.w,
                        q2.x, q2.y, q2.z, q2.w, q3.x, q3.y, q3.z, q3.w};
#pragma unroll
      for (int kx = 0; kx < 6; kx++) {
        const float* wb = s_w + ((ky * 6 + kx) * 3 + c) * 32 + cg * 8;
        float4 wva = *(const float4*)wb;
        float4 wvb = *(const float4*)(wb + 4);
        float wv[8] = {wva.x, wva.y, wva.z, wva.w, wvb.x, wvb.y, wvb.z, wvb.w};
#pragma unroll
        for (int k = 0; k < 8; k++)
#pragma unroll
          for (int j = 0; j < 8; j++) acc[k][j] = fmaf(iv16[kx + k], wv[j], acc[k][j]);
      }
    }
  }
  float pm[4][8];
#pragma unroll
  for (int kk = 0; kk < 4; kk++)
#pragma unroll
    for (int j = 0; j < 8; j++) pm[kk][j] = fmaxf(acc[2 * kk][j], acc[2 * kk + 1][j]);
#pragma unroll
  for (int kk = 0; kk < 4; kk++)
#pragma unroll
    for (int j = 0; j < 8; j++) {
      float o = __shfl_down(pm[kk][j], 4);
      pm[kk][j] = fmaxf(pm[kk][j], o);
    }
  if (!(py & 1)) {
    int pyp = ty * 8 + (py >> 1);
    if (pyp < 77) {
#pragma unroll
      for (int kk = 0; kk < 4; kk++) {
        int pxp = tx * 16 + (l & 3) * 4 + kk;
        if (pxp < 117) {
          float* op = out + ((size_t)(n * 77 + pyp) * 117 + pxp) * 32 + cg * 8;
          float4 v0, v1;
          v0.x = fmaxf(pm[kk][0], 0.f); v0.y = fmaxf(pm[kk][1], 0.f);
          v0.z = fmaxf(pm[kk][2], 0.f); v0.w = fmaxf(pm[kk][3], 0.f);
          v1.x = fmaxf(pm[kk][4], 0.f); v1.y = fmaxf(pm[kk][5], 0.f);
          v1.z = fmaxf(pm[kk][6], 0.f); v1.w = fmaxf(pm[kk][7], 0.f);
          ((float4*)op)[0] = v0;
          ((float4*)op)[1] = v1;
        }
      }
    }
  }
}

// ---------------- conv2 3x3x32->64 + fused 2x2 maxpool (256 thr, 4ch/thread) ------
__global__ __launch_bounds__(256) void k_conv2p(const float* __restrict__ in,
    const float* __restrict__ w, const float* __restrict__ bias, float* __restrict__ out) {
  __shared__ float s_in[32 * 10 * 20];  // [c][y][x] padded rows
  int tx = blockIdx.x, ty = blockIdx.y, n = blockIdx.z;
  int tid = threadIdx.x;
  int iy0 = ty * 8, ix0 = tx * 16;
  for (int idx = tid; idx < 10 * 18 * 32; idx += 256) {
    int c = idx & 31;
    int rem = idx >> 5;
    int x = rem % 18, y = rem / 18;
    int gy = iy0 + y, gx = ix0 + x;
    float v = 0.f;
    if (gy < 77 && gx < 117) v = in[((size_t)(n * 77 + gy) * 117 + gx) * 32 + c];
    s_in[c * 200 + y * 20 + x] = v;
  }
  __syncthreads();

  int cg = tid >> 4;   // 16 groups x 4 out-ch
  int pg = tid & 15;
  int py = pg >> 1;
  int px0 = (pg & 1) * 8;

  float acc[8][4];
  float bj[4];
#pragma unroll
  for (int j = 0; j < 4; j++) bj[j] = bias[cg * 4 + j];
#pragma unroll
  for (int k = 0; k < 8; k++)
#pragma unroll
    for (int j = 0; j < 4; j++) acc[k][j] = bj[j];

#pragma unroll 1
  for (int ky = 0; ky < 3; ky++) {
#pragma unroll 2
    for (int c = 0; c < 32; c++) {
      const float* ib = s_in + c * 200 + (py + ky) * 20 + px0;
      float4 q0 = ((const float4*)ib)[0];
      float4 q1 = ((const float4*)ib)[1];
      float4 q2 = ((const float4*)ib)[2];
      float iv12[12] = {q0.x, q0.y, q0.z, q0.w, q1.x, q1.y, q1.z, q1.w,
                        q2.x, q2.y, q2.z, q2.w};
#pragma unroll
      for (int kx = 0; kx < 3; kx++) {
        float4 wa = *(const float4*)(w + (size_t)((ky * 3 + kx) * 32 + c) * 64 + cg * 4);
#pragma unroll
        for (int k = 0; k < 8; k++) {
          acc[k][0] = fmaf(iv12[kx + k], wa.x, acc[k][0]);
          acc[k][1] = fmaf(iv12[kx + k], wa.y, acc[k][1]);
          acc[k][2] = fmaf(iv12[kx + k], wa.z, acc[k][2]);
          acc[k][3] = fmaf(iv12[kx + k], wa.w, acc[k][3]);
        }
      }
    }
  }
  float pm[4][4];
#pragma unroll
  for (int kk = 0; kk < 4; kk++)
#pragma unroll
    for (int j = 0; j < 4; j++) pm[kk][j] = fmaxf(acc[2 * kk][j], acc[2 * kk + 1][j]);
#pragma unroll
  for (int kk = 0; kk < 4; kk++)
#pragma unroll
    for (int j = 0; j < 4; j++) {
      float o = __shfl_down(pm[kk][j], 2);
      pm[kk][j] = fmaxf(pm[kk][j], o);
    }
  if (!(pg & 2)) {
    int pyp = ty * 4 + (py >> 1);
    if (pyp < 37) {
#pragma unroll
      for (int kk = 0; kk < 4; kk++) {
        int pxp = tx * 8 + (pg & 1) * 4 + kk;
        if (pxp < 57) {
          float* op = out + ((size_t)(n * 37 + pyp) * 57 + pxp) * 64 + cg * 4;
          float4 v0;
          v0.x = fmaxf(pm[kk][0], 0.f); v0.y = fmaxf(pm[kk][1], 0.f);
          v0.z = fmaxf(pm[kk][2], 0.f); v0.w = fmaxf(pm[kk][3], 0.f);
          ((float4*)op)[0] = v0;
        }
      }
    }
  }
}

// ---------------- conv3: 3x3x64 -> 128, 4-row tiles, channel-split x2 ----------------
__global__ __launch_bounds__(256) void k_conv3(const float* __restrict__ in,
    const float* __restrict__ w, const float* __restrict__ bias, float* __restrict__ out) {
  __shared__ float s_in[64 * 6 * 20];  // [c][y][x] padded rows
  int tx = blockIdx.x, ty = blockIdx.y, z = blockIdx.z;
  int n = z >> 1, h = z & 1;
  int tid = threadIdx.x;
  int iy0 = ty * 4, ix0 = tx * 16;
  for (int idx = tid; idx < 6 * 18 * 64; idx += 256) {
    int c = idx & 63;
    int rem = idx >> 6;
    int x = rem % 18, y = rem / 18;
    int gy = iy0 + y, gx = ix0 + x;
    float v = 0.f;
    if (gy < 37 && gx < 57) v = in[((size_t)(n * 37 + gy) * 57 + gx) * 64 + c];
    s_in[c * 120 + y * 20 + x] = v;
  }
  __syncthreads();

  int cg = tid >> 4;
  int pg = tid & 15;
  int py = pg >> 2;
  int px0 = (pg & 3) * 4;
  int ob = h * 64 + cg * 4;

  float acc[4][4];
  float bj[4];
#pragma unroll
  for (int j = 0; j < 4; j++) bj[j] = bias[ob + j];
#pragma unroll
  for (int k = 0; k < 4; k++)
#pragma unroll
    for (int j = 0; j < 4; j++) acc[k][j] = bj[j];

#pragma unroll 1
  for (int ky = 0; ky < 3; ky++) {
#pragma unroll 2
    for (int c = 0; c < 64; c++) {
      const float* ib = s_in + c * 120 + (py + ky) * 20 + px0;
      float4 q0 = ((const float4*)ib)[0];
      float4 q1 = ((const float4*)ib)[1];
      float iv8[8] = {q0.x, q0.y, q0.z, q0.w, q1.x, q1.y, q1.z, q1.w};
#pragma unroll
      for (int kx = 0; kx < 3; kx++) {
        float4 wa = *(const float4*)(w + (size_t)((ky * 3 + kx) * 64 + c) * 128 + ob);
#pragma unroll
        for (int k = 0; k < 4; k++) {
          acc[k][0] = fmaf(iv8[kx + k], wa.x, acc[k][0]);
          acc[k][1] = fmaf(iv8[kx + k], wa.y, acc[k][1]);
          acc[k][2] = fmaf(iv8[kx + k], wa.z, acc[k][2]);
          acc[k][3] = fmaf(iv8[kx + k], wa.w, acc[k][3]);
        }
      }
    }
  }
  int oy = iy0 + py;
  if (oy < 35) {
#pragma unroll
    for (int k = 0; k < 4; k++) {
      int ox = ix0 + px0 + k;
      if (ox < 55) {
        float* op = out + ((size_t)(n * 35 + oy) * 55 + ox) * 128 + ob;
        float4 v0;
        v0.x = fmaxf(acc[k][0], 0.f); v0.y = fmaxf(acc[k][1], 0.f);
        v0.z = fmaxf(acc[k][2], 0.f); v0.w = fmaxf(acc[k][3], 0.f);
        ((float4*)op)[0] = v0;
      }
    }
  }
}

// ---------------- dense1: (8,246400) @ (246400,256), split-K, x staged in LDS ----------------
__global__ __launch_bounds__(256) void k_dense1(const float* __restrict__ a3,
    const float* __restrict__ wd1, float* __restrict__ part) {
  __shared__ float red[4][64][33];  // +1 pad: kill 32-way bank conflicts
  __shared__ float s_x[256][8];
  int c = blockIdx.x;
  int tid = threadIdx.x;
  int c4 = tid & 63;
  int ks = tid >> 6;
  int k0 = c * 256;
  int kn = 246400 - k0;
  if (kn > 256) kn = 256;
  for (int idx = tid; idx < 2048; idx += 256) {
    int nn = idx >> 8, r = idx & 255;
    int rr = k0 + r;
    if (rr > 246399) rr = 246399;
    s_x[r][nn] = a3[(size_t)nn * 246400 + rr];
  }
  __syncthreads();
  float acc[8][4];
#pragma unroll
  for (int n = 0; n < 8; n++)
#pragma unroll
    for (int j = 0; j < 4; j++) acc[n][j] = 0.f;
  int kbeg = ks * 64;
  int kend = kbeg + 64;
  if (kend > kn) kend = kn;
#pragma unroll 8
  for (int kk = kbeg; kk < kend; kk++) {
    float4 wv = *(const float4*)(wd1 + (size_t)(k0 + kk) * 256 + c4 * 4);
    float4 xa = *(const float4*)&s_x[kk][0];
    float4 xb = *(const float4*)&s_x[kk][4];
    float xs[8] = {xa.x, xa.y, xa.z, xa.w, xb.x, xb.y, xb.z, xb.w};
#pragma unroll
    for (int n = 0; n < 8; n++) {
      acc[n][0] = fmaf(xs[n], wv.x, acc[n][0]);
      acc[n][1] = fmaf(xs[n], wv.y, acc[n][1]);
      acc[n][2] = fmaf(xs[n], wv.z, acc[n][2]);
      acc[n][3] = fmaf(xs[n], wv.w, acc[n][3]);
    }
  }
#pragma unroll
  for (int n = 0; n < 8; n++)
#pragma unroll
    for (int j = 0; j < 4; j++) red[ks][c4][n * 4 + j] = acc[n][j];
  __syncthreads();
  for (int o = tid; o < 2048; o += 256) {
    int col = o & 255, n = o >> 8;
    int cc = col >> 2, j = col & 3;
    float s = red[0][cc][n * 4 + j] + red[1][cc][n * 4 + j] +
              red[2][cc][n * 4 + j] + red[3][cc][n * 4 + j];
    part[(size_t)c * 2048 + n * 256 + col] = s;
  }
}

// ---------------- reduce1 stage A: 16 c-chunks x 2048, coalesced ----------------
__global__ __launch_bounds__(256) void k_reduce1a(const float* __restrict__ part,
    float* __restrict__ partr) {
  int bx = blockIdx.x;
  int t = blockIdx.y * 256 + threadIdx.x;
  int cbeg = bx * 61;
  int cend = cbeg + 61;
  if (cend > 963) cend = 963;
  float s = 0.f;
#pragma unroll 8
  for (int c = cbeg; c < cend; c++) s += part[(size_t)c * 2048 + t];
  partr[(size_t)bx * 2048 + t] = s;
}

// ---------------- dense2 + reduce1b + transform fused ----------------
__global__ __launch_bounds__(256) void k_dense2t(const float* __restrict__ partr,
    const float* __restrict__ bd1, const float* __restrict__ wd2,
    const float* __restrict__ bd2, float* __restrict__ pred,
    float4* __restrict__ boxd4, float* __restrict__ meta) {
  __shared__ float red[8][32][33];  // padded
  __shared__ float s_d1[256][8];
  int jb = blockIdx.x;  // 0..299
  int tid = threadIdx.x;
  for (int idx = tid; idx < 2048; idx += 256) {
    int n = idx >> 8, j = idx & 255;
    float s = 0.f;
#pragma unroll
    for (int b = 0; b < 16; b++) s += partr[b * 2048 + idx];
    s_d1[j][n] = fmaxf(s + bd1[j], 0.f);
  }
  __syncthreads();
  int c4 = tid & 31;
  int ks = tid >> 5;
  int j0 = jb * 128 + c4 * 4;
  float acc[8][4];
#pragma unroll
  for (int n = 0; n < 8; n++)
#pragma unroll
    for (int j = 0; j < 4; j++) acc[n][j] = 0.f;
#pragma unroll 8
  for (int kk = 0; kk < 32; kk++) {
    int row = ks * 32 + kk;
    float4 wv = *(const float4*)(wd2 + (size_t)row * 38400 + j0);
    float4 xa = *(const float4*)&s_d1[row][0];
    float4 xb = *(const float4*)&s_d1[row][4];
    float xs[8] = {xa.x, xa.y, xa.z, xa.w, xb.x, xb.y, xb.z, xb.w};
#pragma unroll
    for (int n = 0; n < 8; n++) {
      acc[n][0] = fmaf(xs[n], wv.x, acc[n][0]);
      acc[n][1] = fmaf(xs[n], wv.y, acc[n][1]);
      acc[n][2] = fmaf(xs[n], wv.z, acc[n][2]);
      acc[n][3] = fmaf(xs[n], wv.w, acc[n][3]);
    }
  }
#pragma unroll
  for (int n = 0; n < 8; n++)
#pragma unroll
    for (int j = 0; j < 4; j++) red[ks][c4][n * 4 + j] = acc[n][j];
  __syncthreads();
  if (tid >= 64) return;
  int n = tid >> 3, cc = tid & 7;
  int cell = jb * 8 + cc;  // 0..2399
  float v[16];
#pragma unroll
  for (int q = 0; q < 16; q++) {
    int lc = cc * 16 + q;
    int cq = lc >> 2, jq = lc & 3;
    float s = 0.f;
#pragma unroll
    for (int g = 0; g < 8; g++) s += red[g][cq][n * 4 + jq];
    v[q] = s + bd2[jb * 128 + lc];
  }
  float gx = (float)(cell % 60), gy = (float)(cell / 60);
  float o[16];
  o[0] = (sigmoidf_(v[0]) + gx) * 4.0f;
  o[1] = (sigmoidf_(v[1]) + gy) * 4.0f;
  o[2] = expf(v[2]) * 60.0f * 4.0f;
  o[3] = expf(v[3]) * 30.0f * 4.0f;
  o[4] = sigmoidf_(v[4]);
  o[5] = sigmoidf_(v[5]);
  o[6] = sigmoidf_(v[6]);
  o[7] = sigmoidf_(v[7]);
  o[8] = (v[8] + gx) * 4.0f;
  o[9] = (v[9] + gy) * 4.0f;
  o[10] = expf(v[10]) * 20.0f * 4.0f;
  o[11] = expf(v[11]) * 40.0f * 4.0f;
  o[12] = v[12];
  o[13] = sigmoidf_(v[13]);
  o[14] = sigmoidf_(v[14]);
  o[15] = sigmoidf_(v[15]);
  float* op = pred + ((size_t)n * 2400 + cell) * 16;
#pragma unroll
  for (int q4 = 0; q4 < 4; q4++) {
    float4 w4;
    w4.x = o[q4 * 4 + 0]; w4.y = o[q4 * 4 + 1];
    w4.z = o[q4 * 4 + 2]; w4.w = o[q4 * 4 + 3];
    ((float4*)op)[q4] = w4;
  }
#pragma unroll
  for (int h = 0; h < 2; h++) {
    int b = n * 4800 + h * 2400 + cell;
    float X = o[h * 8 + 0], Y = o[h * 8 + 1], W = o[h * 8 + 2], H = o[h * 8 + 3];
    float conf = o[h * 8 + 4];
    float c0 = o[h * 8 + 5], c1 = o[h * 8 + 6], c2 = o[h * 8 + 7];
    int cls = 0; float best = c0;
    if (c1 > best) { best = c1; cls = 1; }
    if (c2 > best) { best = c2; cls = 2; }
    float x1 = X - W / 2.0f, y1 = Y - H / 2.0f;
    float x2 = X + W / 2.0f, y2 = Y + H / 2.0f;
    boxd4[b] = make_float4(x1, y1, x2, y2);
    meta[2 * b] = conf;
    ((int*)meta)[2 * b + 1] = cls;
  }
}

// ---------------- NMS stage 1: zero keep + compact + sort (512 thr) ----------------
__global__ __launch_bounds__(512) void k_nms_sort(const float4* __restrict__ boxd4,
    const float* __restrict__ meta, int* __restrict__ cnt,
    float4* __restrict__ sbf, int* __restrict__ sidx, float* __restrict__ keep_out) {
  __shared__ unsigned long long key[8192];
  __shared__ int scnt;
  int bid = blockIdx.x;  // 0..23
  int n = bid / 3, c = bid - n * 3;
  int tid = threadIdx.x;
  float* ko = keep_out + (size_t)bid * 4800;
  for (int s = tid; s < 4800; s += 512) ko[s] = 0.f;
  if (tid == 0) scnt = 0;
  __syncthreads();

  const float* mt = meta + (size_t)n * 9600;
  for (int p = tid; p < 4800; p += 512) {
    float2 m = ((const float2*)mt)[p];
    float conf = m.x;
    int cls = __float_as_int(m.y);
    if (conf > 0.5f && cls == c) {
      int slot = atomicAdd(&scnt, 1);
      unsigned u = __float_as_uint(conf);
      unsigned asc = (u & 0x80000000u) ? ~u : (u | 0x80000000u);
      key[slot] = (((unsigned long long)(~asc)) << 32) | (unsigned)p;
    }
  }
  __syncthreads();
  int V = scnt;
  if (tid == 0) cnt[bid] = V;
  if (V == 0) return;
  int Vp2 = 1;
  while (Vp2 < V) Vp2 <<= 1;
  for (int s = V + tid; s < Vp2; s += 512) key[s] = ~0ull;

  // bitonic sort ascending -> score desc, idx asc (stable argsort(-score))
  for (int k = 2; k <= Vp2; k <<= 1) {
    for (int j = k >> 1; j > 0; j >>= 1) {
      __syncthreads();
      int jm = j - 1;
      for (int t2 = tid; t2 < (Vp2 >> 1); t2 += 512) {
        int i = ((t2 & ~jm) << 1) | (t2 & jm);
        int q = i | j;
        bool up = ((i & k) == 0);
        unsigned long long a = key[i], b2 = key[q];
        if ((a > b2) == up) { key[i] = b2; key[q] = a; }
      }
    }
  }
  __syncthreads();
  float4* sb = sbf + (size_t)bid * 4800;
  int* si = sidx + (size_t)bid * 4800;
  const float4* bsrc = boxd4 + (size_t)n * 4800;
  for (int s = tid; s < V; s += 512) {
    unsigned p = (unsigned)(key[s] & 0xFFFFFFFFull);
    sb[s] = bsrc[p];
    si[s] = (int)p;
  }
}

// ---------------- NMS stage 2: grid-parallel suppression bit-matrix ----------------
// grid (24, 16, 4): block = (nc, word-column w, row-quarter). Disjoint mat writes.
__global__ __launch_bounds__(256) void k_iou_mat(const int* __restrict__ cnt,
    const float4* __restrict__ sbf, unsigned long long* __restrict__ mat) {
  int nc = blockIdx.x;
  int w = blockIdx.y;
  int rz = blockIdx.z;
  int V = cnt[nc];
  if (V == 0 || V > 1024) return;
  int W = (V + 63) >> 6;
  if (w >= W) return;
  int chunk = (V + 3) >> 2;
  int rbeg = rz * chunk;
  int rend = rbeg + chunk;
  if (rend > V) rend = V;
  if (rbeg >= rend) return;
  int tid = threadIdx.x;
  int l = tid & 63, wv = tid >> 6;
  const float4* sb = sbf + (size_t)nc * 4800;
  int col = (w << 6) + l;
  float4 bj = sb[col < V ? col : (V - 1)];
  float aj = (bj.z - bj.x + 1.0f) * (bj.w - bj.y + 1.0f);
  unsigned long long* mrow = mat + (size_t)nc * 1024 * 16 + w;
  for (int i = rbeg + wv; i < rend; i += 4) {
    float4 bi = sb[i];  // wave-uniform, L2-hot
    float iw = fminf(bi.z, bj.z) - fmaxf(bi.x, bj.x) + 1.0f;
    float ih = fminf(bi.w, bj.w) - fmaxf(bi.y, bj.y) + 1.0f;
    iw = fmaxf(iw, 0.f);
    ih = fmaxf(ih, 0.f);
    float inter = iw * ih;
    float ai = (bi.z - bi.x + 1.0f) * (bi.w - bi.y + 1.0f);
    float iou = inter / (ai + aj - inter);
    bool pr = (col > i) && (col < V) && (iou >= 0.4f);
    unsigned long long word = __ballot(pr);
    if (l == 0) mrow[(size_t)i * 16] = word;
  }
}

// ---------------- NMS stage 3: linear greedy scan, VALU-only serial chain ----------------
__global__ __launch_bounds__(256) void k_nms_scan(const int* __restrict__ cnt,
    const unsigned long long* __restrict__ mat, const float4* __restrict__ sbf,
    const int* __restrict__ sidx, float* __restrict__ keep_out) {
  __shared__ float4 sbL[4800];            // slow-path staging
  __shared__ unsigned long long avail[75];
  int nc = blockIdx.x;
  int V = cnt[nc];
  if (V == 0) return;
  int tid = threadIdx.x;
  float* ko = keep_out + (size_t)nc * 4800;
  const int* si = sidx + (size_t)nc * 4800;

  if (V <= 1024) {
    if (tid >= 64) return;
    int l = tid;
    int W = (V + 63) >> 6;
    const unsigned long long* mbase = mat + (size_t)nc * 1024 * 16;
    bool act = (l < W);
    unsigned long long av = 0ull;  // lane l holds avail word l
    if (act) {
      int rem = V - (l << 6);
      av = (rem >= 64) ? ~0ull : ((1ull << rem) - 1ull);
    }
    unsigned long long mA[16], mB[16];
#pragma unroll
    for (int k = 0; k < 16; k++)
      mA[k] = (act && k < V) ? mbase[(size_t)k * 16 + l] : 0ull;
    for (int i0 = 0; i0 < V; i0 += 16) {
      int nx = i0 + 16;
#pragma unroll
      for (int k = 0; k < 16; k++)
        mB[k] = (act && (nx + k) < V) ? mbase[(size_t)(nx + k) * 16 + l] : 0ull;
      int wi = i0 >> 6;
      unsigned long long mloc[16];
#pragma unroll
      for (int k = 0; k < 16; k++) mloc[k] = __shfl(mA[k], wi, 64);
      unsigned long long cur = __shfl(av, wi, 64);
      unsigned alive = 0;
#pragma unroll
      for (int k = 0; k < 16; k++) {
        int i = i0 + k;
        if (i < V && ((cur >> (i & 63)) & 1ull)) {
          alive |= 1u << k;
          cur &= ~mloc[k];
        }
      }
#pragma unroll
      for (int k = 0; k < 16; k++)
        if ((alive >> k) & 1u) av &= ~mA[k];
      if (l < 16 && ((alive >> l) & 1u) && (i0 + l) < V) ko[si[i0 + l]] = 1.0f;
#pragma unroll
      for (int k = 0; k < 16; k++) mA[k] = mB[k];
    }
    return;
  }

  // slow path (V > 1024): r6-validated single-wave greedy
  {
    const float4* sb = sbf + (size_t)nc * 4800;
    for (int s = tid; s < V; s += 256) sbL[s] = sb[s];
    for (int w = tid; w < 75; w += 256) {
      int rem = V - (w << 6);
      avail[w] = (rem >= 64) ? ~0ull : (rem <= 0 ? 0ull : ((1ull << rem) - 1ull));
    }
    __syncthreads();
    if (tid >= 64) return;
    int l = tid;
    int wlast = (V - 1) >> 6;
    for (;;) {
      int cand = 0x7FFFFFFF;
      unsigned long long a0 = avail[l];
      if (a0) cand = (l << 6) + __ffsll((long long)a0) - 1;
      if (l < 11) {
        unsigned long long a1 = avail[64 + l];
        if (a1) {
          int c2 = ((64 + l) << 6) + __ffsll((long long)a1) - 1;
          if (c2 < cand) cand = c2;
        }
      }
#pragma unroll
      for (int off = 32; off > 0; off >>= 1) {
        int o = __shfl_xor(cand, off, 64);
        if (o < cand) cand = o;
      }
      if (cand == 0x7FFFFFFF) break;
      int i = cand;
      int tw = i >> 6;
      if (l == 0) {
        ko[si[i]] = 1.0f;
        avail[tw] &= ~(1ull << (i & 63));
      }
      float4 bi = sbL[i];
      float ai = (bi.z - bi.x + 1.0f) * (bi.w - bi.y + 1.0f);
      for (int w = tw; w <= wlast; w++) {
        unsigned long long aw = avail[w];
        if (!aw) continue;
        int col = (w << 6) + l;
        float4 bj = sbL[col];
        float iw = fminf(bi.z, bj.z) - fmaxf(bi.x, bj.x) + 1.0f;
        float ih = fminf(bi.w, bj.w) - fmaxf(bi.y, bj.y) + 1.0f;
        iw = fmaxf(iw, 0.f);
        ih = fmaxf(ih, 0.f);
        float inter = iw * ih;
        float aj = (bj.z - bj.x + 1.0f) * (bj.w - bj.y + 1.0f);
        float iou = inter / (ai + aj - inter);
        bool pr = (col > i) && (col < V) && (iou >= 0.4f);
        unsigned long long word = __ballot(pr);
        if (word && l == 0) avail[w] = aw & ~word;
      }
    }
  }
}

extern "C" void kernel_launch(void* const* d_in, const int* in_sizes, int n_in,
                              void* d_out, int out_size, void* d_ws, size_t ws_size,
                              hipStream_t stream) {
  const float* img = (const float*)d_in[0];
  const float* w1 = (const float*)d_in[1];
  const float* b1 = (const float*)d_in[2];
  const float* w2 = (const float*)d_in[3];
  const float* b2 = (const float*)d_in[4];
  const float* w3 = (const float*)d_in[5];
  const float* b3 = (const float*)d_in[6];
  const float* wd1 = (const float*)d_in[7];
  const float* bd1 = (const float*)d_in[8];
  const float* wd2 = (const float*)d_in[9];
  const float* bd2 = (const float*)d_in[10];

  float* ws = (float*)d_ws;
  float* a3 = ws + 0;                       // 1,971,200
  float* pd1 = ws + 3942400;                // 1,972,224 (dead after reduce1a)
  float* partr = ws + 5914624;              // 32,768
  float4* boxd4 = (float4*)(ws + 5947392);  // 153,600 floats
  float* meta = ws + 6100992;               // 76,800
  float4* sbf = (float4*)(ws + 6177792);    // 460,800
  int* sidx = (int*)(ws + 6638592);         // 115,200
  int* cnt = (int*)(ws + 6753792);          // 24
  float* p1 = ws + 9324800;                 // 2,306,304 pooled conv1
  float* p2 = ws + 16047104;                // 1,079,808 pooled conv2
  unsigned long long* mat = (unsigned long long*)(ws + 3942400);  // overlays pd1

  float* pred = (float*)d_out;
  float* keep = pred + 307200;

  k_conv1p<<<dim3(8, 10, 8), 256, 0, stream>>>(img, w1, b1, p1);
  k_conv2p<<<dim3(8, 10, 8), 256, 0, stream>>>(p1, w2, b2, p2);
  k_conv3<<<dim3(4, 9, 16), 256, 0, stream>>>(p2, w3, b3, a3);
  k_dense1<<<963, 256, 0, stream>>>(a3, wd1, pd1);
  k_reduce1a<<<dim3(16, 8), 256, 0, stream>>>(pd1, partr);
  k_dense2t<<<300, 256, 0, stream>>>(partr, bd1, wd2, bd2, pred, boxd4, meta);
  k_nms_sort<<<24, 512, 0, stream>>>(boxd4, meta, cnt, sbf, sidx, keep);
  k_iou_mat<<<dim3(24, 16, 4), 256, 0, stream>>>(cnt, sbf, mat);
  k_nms_scan<<<24, 256, 0, stream>>>(cnt, mat, sbf, sidx, keep);
}